// Round 3
// baseline (120.230 us; speedup 1.0000x reference)
//
#include <hip/hip_runtime.h>
#include <stdint.h>

typedef _Float16 half8 __attribute__((ext_vector_type(8)));
typedef _Float16 half4_t __attribute__((ext_vector_type(4)));
typedef float f32x4 __attribute__((ext_vector_type(4)));
typedef float f32x2 __attribute__((ext_vector_type(2)));

#define N_ 32
#define C_ 8
#define W_ 65536
#define F_ 16
#define OW_ 65473
#define K_ 512
#define XSLICE 192            // halfs per channel per wave slice (128 tile + 64 halo)
#define WL_HALFS 8192

// funnel16(hi, lo) = (hi:lo) >> 16  -> v_alignbit_b32
__device__ __forceinline__ uint32_t funnel16(uint32_t hi, uint32_t lo) {
  return (uint32_t)((((uint64_t)hi << 32) | (uint64_t)lo) >> 16);
}

// w LDS swizzle (half-index, mult of 4): XOR chunk idx with its own bits 6-8
__device__ __forceinline__ uint32_t wswz(uint32_t e) {
  uint32_t ch = e >> 3;
  ch ^= (ch >> 6) & 7u;
  return (ch << 4) | ((e & 7u) << 1);
}

// x-slice swizzle on 16B chunks (byte offset relative to wave's region)
__device__ __forceinline__ uint32_t xswz(uint32_t byteoff) {
  uint32_t ch = byteoff >> 4;
  ch ^= (ch >> 3) & 7u;
  return (byteoff & 15u) | (ch << 4);
}

__global__ __launch_bounds__(256, 4)
void corr1d_mfma(const float* __restrict__ x, const float* __restrict__ w,
                 const float* __restrict__ b, float* __restrict__ out) {
  __shared__ __align__(16) _Float16 wl[WL_HALFS];        // 16 KB shared w
  __shared__ __align__(16) _Float16 xsl[4][8 * XSLICE];  // 4 x 3 KB per-wave

  const int tid  = threadIdx.x;
  const int lane = tid & 63;
  const int wv   = tid >> 6;
  const int c15  = lane & 15;
  const int g    = lane >> 4;
  const int cc   = lane >> 3;          // staging: channel 0..7
  const int p0   = (lane & 7) * 24;    // staging: 24 f32 per lane

  const int n   = blockIdx.x >> 5;
  const int tw0 = ((blockIdx.x & 31) << 11) + (wv << 9);  // wave's 512-t strip

  const float* xn = x + (size_t)n * (C_ * W_);
  char* xwb = reinterpret_cast<char*>(xsl[wv]);

  // ---- stage w once (cooperative), f32 -> f16 swizzled ----
  #pragma unroll
  for (int j = 0; j < 8; ++j) {
    int e = (tid + 256 * j) * 4;
    f32x4 v = *reinterpret_cast<const f32x4*>(w + e);
    half4_t h; h[0] = (_Float16)v[0]; h[1] = (_Float16)v[1];
    h[2] = (_Float16)v[2]; h[3] = (_Float16)v[3];
    *reinterpret_cast<half4_t*>(reinterpret_cast<char*>(wl) + wswz((uint32_t)e)) = h;
  }

  // ---- stage x subtile 0 (per-wave private) ----
  {
    f32x4 xr0[6];
    #pragma unroll
    for (int j = 0; j < 6; ++j) {
      int gi = tw0 + p0 + 4 * j;
      xr0[j] = (gi < W_) ? *reinterpret_cast<const f32x4*>(xn + cc * W_ + gi)
                         : (f32x4){0.f, 0.f, 0.f, 0.f};
    }
    uint32_t base = (uint32_t)(cc * XSLICE + p0) * 2u;
    #pragma unroll
    for (int j2 = 0; j2 < 3; ++j2) {
      half8 h;
      h[0] = (_Float16)xr0[2*j2][0]; h[1] = (_Float16)xr0[2*j2][1];
      h[2] = (_Float16)xr0[2*j2][2]; h[3] = (_Float16)xr0[2*j2][3];
      h[4] = (_Float16)xr0[2*j2+1][0]; h[5] = (_Float16)xr0[2*j2+1][1];
      h[6] = (_Float16)xr0[2*j2+1][2]; h[7] = (_Float16)xr0[2*j2+1][3];
      *reinterpret_cast<half8*>(xwb + xswz(base + 16 * j2)) = h;
    }
  }

  const f32x4 bv4 = *reinterpret_cast<const f32x4*>(b + 4 * g);

  __syncthreads();   // the ONLY barrier: w (and own x) ready

  union Win { half8 h[2]; uint32_t d[8]; };
  f32x4 xr[6];

  for (int i = 0; i < 4; ++i) {
    // T14 issue-early: next subtile's global loads in flight during compute
    if (i < 3) {
      const int t0n = tw0 + 128 * (i + 1);
      #pragma unroll
      for (int j = 0; j < 6; ++j) {
        int gi = t0n + p0 + 4 * j;
        xr[j] = (gi < W_) ? *reinterpret_cast<const f32x4*>(xn + cc * W_ + gi)
                          : (f32x4){0.f, 0.f, 0.f, 0.f};
      }
    }

    f32x4 acc[8];
    #pragma unroll
    for (int r = 0; r < 8; ++r) acc[r] = (f32x4){0.f, 0.f, 0.f, 0.f};

    // ---- K loop: 16 k-steps of 32; tile r cols at t = t0 + r + 8*col ----
    #pragma unroll
    for (int s = 0; s < 16; ++s) {
      const uint32_t we = (uint32_t)(c15 * K_ + 32 * s + 8 * g);
      const half8 wf = *reinterpret_cast<const half8*>(
                           reinterpret_cast<const char*>(wl) + wswz(we));
      const int cst = s >> 1;
      const int jb  = (s & 1) * 32;
      const int A0  = 8 * c15 + jb + 8 * g;   // mult of 8 -> 16B chunks
      uint32_t xb0 = (uint32_t)(cst * XSLICE + A0) * 2u;
      Win win;
      win.h[0] = *reinterpret_cast<const half8*>(xwb + xswz(xb0));
      win.h[1] = *reinterpret_cast<const half8*>(xwb + xswz(xb0 + 16));
      #pragma unroll
      for (int r = 0; r < 8; ++r) {
        union { uint32_t d[4]; half8 h; } fr;
        const int m = r >> 1;
        if ((r & 1) == 0) {
          fr.d[0] = win.d[m];     fr.d[1] = win.d[m + 1];
          fr.d[2] = win.d[m + 2]; fr.d[3] = win.d[m + 3];
        } else {
          fr.d[0] = funnel16(win.d[m + 1], win.d[m]);
          fr.d[1] = funnel16(win.d[m + 2], win.d[m + 1]);
          fr.d[2] = funnel16(win.d[m + 3], win.d[m + 2]);
          fr.d[3] = funnel16(win.d[m + 4], win.d[m + 3]);
        }
        acc[r] = __builtin_amdgcn_mfma_f32_16x16x32_f16(wf, fr.h, acc[r], 0, 0, 0);
      }
    }

    // write-late: stage next subtile into the (now fully-read) private slice
    if (i < 3) {
      uint32_t base = (uint32_t)(cc * XSLICE + p0) * 2u;
      #pragma unroll
      for (int j2 = 0; j2 < 3; ++j2) {
        half8 h;
        h[0] = (_Float16)xr[2*j2][0]; h[1] = (_Float16)xr[2*j2][1];
        h[2] = (_Float16)xr[2*j2][2]; h[3] = (_Float16)xr[2*j2][3];
        h[4] = (_Float16)xr[2*j2+1][0]; h[5] = (_Float16)xr[2*j2+1][1];
        h[6] = (_Float16)xr[2*j2+1][2]; h[7] = (_Float16)xr[2*j2+1][3];
        *reinterpret_cast<half8*>(xwb + xswz(base + 16 * j2)) = h;
      }
    }

    // ---- epilogue: register-transpose stores, alignment-exact per q ----
    // addr mod 16 = 4*((f+t) mod 4), f = 4g+q, t run starts at T (mult of 8)
    const int T = tw0 + 128 * i + 8 * c15;
    #pragma unroll
    for (int q = 0; q < 4; ++q) {
      const float bias = 8.0f * bv4[q];   // reference adds bias C times
      float sv[8];
      #pragma unroll
      for (int j = 0; j < 8; ++j) sv[j] = acc[j][q] + bias;
      float* row = out + (size_t)(n * F_ + 4 * g + q) * OW_ + T;
      if (T + 8 <= OW_) {
        if (q == 0) {            // 16B aligned
          *reinterpret_cast<f32x4*>(row)     = (f32x4){sv[0], sv[1], sv[2], sv[3]};
          *reinterpret_cast<f32x4*>(row + 4) = (f32x4){sv[4], sv[5], sv[6], sv[7]};
        } else if (q == 2) {     // 8B aligned at even offsets
          *reinterpret_cast<f32x2*>(row)     = (f32x2){sv[0], sv[1]};
          *reinterpret_cast<f32x2*>(row + 2) = (f32x2){sv[2], sv[3]};
          *reinterpret_cast<f32x2*>(row + 4) = (f32x2){sv[4], sv[5]};
          *reinterpret_cast<f32x2*>(row + 6) = (f32x2){sv[6], sv[7]};
        } else {                 // q odd: 8B aligned at odd offsets
          row[0] = sv[0];
          *reinterpret_cast<f32x2*>(row + 1) = (f32x2){sv[1], sv[2]};
          *reinterpret_cast<f32x2*>(row + 3) = (f32x2){sv[3], sv[4]};
          *reinterpret_cast<f32x2*>(row + 5) = (f32x2){sv[5], sv[6]};
          row[7] = sv[7];
        }
      } else {
        #pragma unroll
        for (int j = 0; j < 8; ++j) if (T + j < OW_) row[j] = sv[j];
      }
    }
  }
}

extern "C" void kernel_launch(void* const* d_in, const int* in_sizes, int n_in,
                              void* d_out, int out_size, void* d_ws, size_t ws_size,
                              hipStream_t stream) {
  (void)in_sizes; (void)n_in; (void)out_size; (void)d_ws; (void)ws_size;
  const float* x = (const float*)d_in[0];
  const float* w = (const float*)d_in[1];
  const float* b = (const float*)d_in[2];
  float* out = (float*)d_out;
  corr1d_mfma<<<dim3(32 * 32), dim3(256), 0, stream>>>(x, w, b, out);
}

// Round 5
// 109.826 us; speedup vs baseline: 1.0947x; 1.0947x over previous
//
#include <hip/hip_runtime.h>
#include <stdint.h>

typedef _Float16 half8 __attribute__((ext_vector_type(8)));
typedef __fp16 fp16x2 __attribute__((ext_vector_type(2)));
typedef float f32x4 __attribute__((ext_vector_type(4)));
typedef float f32x2 __attribute__((ext_vector_type(2)));

#define N_ 32
#define C_ 8
#define W_ 65536
#define F_ 16
#define OW_ 65473
#define K_ 512

// funnel16(hi, lo) = (hi:lo) >> 16  -> v_alignbit_b32
__device__ __forceinline__ uint32_t funnel16(uint32_t hi, uint32_t lo) {
  return (uint32_t)((((uint64_t)hi << 32) | (uint64_t)lo) >> 16);
}

// pack two f32 -> one dword of 2x f16 (v_cvt_pkrtz_f16_f32)
__device__ __forceinline__ uint32_t pk(float a, float b) {
  union { fp16x2 h; uint32_t u; } cv;
  cv.h = __builtin_amdgcn_cvt_pkrtz(a, b);
  return cv.u;
}

// One 128-t job for one wave: out[n, :, t0 .. t0+128) (valid-t part).
// B-window per lane: x[c, t0 + 8*c15 + 8*g + jb .. +16) as f16 (cvt from f32).
// A-frag per lane: w[c15, 32*s + 8*g .. +8] as f16.
// Tile mapping (proven in R0-R2): t = t0 + r + 8*col (col = c15), f = 4*g + q.
template<bool GUARD>
__device__ __forceinline__ void job(const float* __restrict__ xn,
                                    const float* __restrict__ w,
                                    const float* __restrict__ b,
                                    float* __restrict__ outn,
                                    int t0, int lane) {
  const int c15 = lane & 15;
  const int g   = lane >> 4;
  const int lanoff = 8 * c15 + 8 * g;

  f32x4 acc[8];
  #pragma unroll
  for (int r = 0; r < 8; ++r) acc[r] = (f32x4){0.f, 0.f, 0.f, 0.f};

  const float* wrow = w + c15 * K_ + 8 * g;   // lane's w row slice (L1-hot)

  #pragma unroll 2
  for (int s = 0; s < 16; ++s) {
    const int c  = s >> 1;
    const int jb = (s & 1) * 32;

    // A-frag: 8 consecutive w f32 -> 8 f16
    f32x4 wa = *reinterpret_cast<const f32x4*>(wrow + 32 * s);
    f32x4 wb = *reinterpret_cast<const f32x4*>(wrow + 32 * s + 4);
    union { uint32_t d[4]; half8 h; } wf;
    wf.d[0] = pk(wa[0], wa[1]); wf.d[1] = pk(wa[2], wa[3]);
    wf.d[2] = pk(wb[0], wb[1]); wf.d[3] = pk(wb[2], wb[3]);

    // B-window: 16 consecutive x f32 (16B-aligned) -> 16 f16
    const float* xp = xn + (size_t)c * W_ + (t0 + jb + lanoff);
    f32x4 raw[4];
    #pragma unroll
    for (int m = 0; m < 4; ++m) {
      if (GUARD) {
        int gi = t0 + jb + lanoff + 4 * m;
        raw[m] = (gi < W_) ? *reinterpret_cast<const f32x4*>(xp + 4 * m)
                           : (f32x4){0.f, 0.f, 0.f, 0.f};
      } else {
        raw[m] = *reinterpret_cast<const f32x4*>(xp + 4 * m);
      }
    }
    union { uint32_t d[8]; half8 h[2]; } win;
    #pragma unroll
    for (int j = 0; j < 8; ++j)
      win.d[j] = pk(raw[j >> 1][(j & 1) * 2], raw[j >> 1][(j & 1) * 2 + 1]);

    // 8 shifted fragments from one window, 8 MFMA
    #pragma unroll
    for (int r = 0; r < 8; ++r) {
      union { uint32_t d[4]; half8 h; } fr;
      const int m = r >> 1;
      if ((r & 1) == 0) {
        fr.d[0] = win.d[m];     fr.d[1] = win.d[m + 1];
        fr.d[2] = win.d[m + 2]; fr.d[3] = win.d[m + 3];
      } else {
        fr.d[0] = funnel16(win.d[m + 1], win.d[m]);
        fr.d[1] = funnel16(win.d[m + 2], win.d[m + 1]);
        fr.d[2] = funnel16(win.d[m + 3], win.d[m + 2]);
        fr.d[3] = funnel16(win.d[m + 4], win.d[m + 3]);
      }
      acc[r] = __builtin_amdgcn_mfma_f32_16x16x32_f16(wf.h, fr.h, acc[r], 0, 0, 0);
    }
  }

  // ---- epilogue: register-transpose stores, alignment-exact per q ----
  // (row + T) mod 16 = 4*((f + T) mod 4) = 4*q  since T is a multiple of 8.
  const f32x4 bv = *reinterpret_cast<const f32x4*>(b + 4 * g);
  const int T = t0 + 8 * c15;
  #pragma unroll
  for (int q = 0; q < 4; ++q) {
    const float bias = 8.0f * bv[q];   // reference adds bias C times
    float sv[8];
    #pragma unroll
    for (int j = 0; j < 8; ++j) sv[j] = acc[j][q] + bias;
    float* row = outn + (size_t)(4 * g + q) * OW_ + T;
    if (T + 8 <= OW_) {
      if (q == 0) {            // 16B aligned
        *reinterpret_cast<f32x4*>(row)     = (f32x4){sv[0], sv[1], sv[2], sv[3]};
        *reinterpret_cast<f32x4*>(row + 4) = (f32x4){sv[4], sv[5], sv[6], sv[7]};
      } else if (q == 2) {     // 8B aligned
        *reinterpret_cast<f32x2*>(row)     = (f32x2){sv[0], sv[1]};
        *reinterpret_cast<f32x2*>(row + 2) = (f32x2){sv[2], sv[3]};
        *reinterpret_cast<f32x2*>(row + 4) = (f32x2){sv[4], sv[5]};
        *reinterpret_cast<f32x2*>(row + 6) = (f32x2){sv[6], sv[7]};
      } else {                 // q odd: dword, then 8B-aligned pairs
        row[0] = sv[0];
        *reinterpret_cast<f32x2*>(row + 1) = (f32x2){sv[1], sv[2]};
        *reinterpret_cast<f32x2*>(row + 3) = (f32x2){sv[3], sv[4]};
        *reinterpret_cast<f32x2*>(row + 5) = (f32x2){sv[5], sv[6]};
        row[7] = sv[7];
      }
    } else {
      #pragma unroll
      for (int j = 0; j < 8; ++j) if (T + j < OW_) row[j] = sv[j];
    }
  }
}

__global__ __launch_bounds__(256, 4)
void corr1d_stream(const float* __restrict__ x, const float* __restrict__ w,
                   const float* __restrict__ b, float* __restrict__ out) {
  const int lane = threadIdx.x & 63;
  const int jw   = blockIdx.x * 4 + (threadIdx.x >> 6);  // wave-job id
  const int n    = jw >> 9;            // 32 n
  const int t0   = (jw & 511) << 7;    // 512 jobs of 128 t per n

  const float* xn   = x + (size_t)n * (C_ * W_);
  float*       outn = out + (size_t)n * F_ * OW_;

  // max x index touched = t0 + 191  -> guard only the last t-job
  if (t0 + 192 <= W_) job<false>(xn, w, b, outn, t0, lane);
  else                job<true >(xn, w, b, outn, t0, lane);
}

extern "C" void kernel_launch(void* const* d_in, const int* in_sizes, int n_in,
                              void* d_out, int out_size, void* d_ws, size_t ws_size,
                              hipStream_t stream) {
  (void)in_sizes; (void)n_in; (void)out_size; (void)d_ws; (void)ws_size;
  const float* x = (const float*)d_in[0];
  const float* w = (const float*)d_in[1];
  const float* b = (const float*)d_in[2];
  float* out = (float*)d_out;
  corr1d_stream<<<dim3(32 * 512 / 4), dim3(256), 0, stream>>>(x, w, b, out);
}

// Round 6
// 58.779 us; speedup vs baseline: 2.0455x; 1.8685x over previous
//
#include <hip/hip_runtime.h>
#include <stdint.h>

typedef _Float16 half8 __attribute__((ext_vector_type(8)));
typedef __fp16 fp16x2 __attribute__((ext_vector_type(2)));
typedef float f32x4 __attribute__((ext_vector_type(4)));
typedef float f32x2 __attribute__((ext_vector_type(2)));
typedef uint32_t u32x2 __attribute__((ext_vector_type(2)));

#define N_ 32
#define C_ 8
#define W_ 65536
#define F_ 16
#define OW_ 65473
#define K_ 512
#define TILE_T 1024
#define XS 1152              // halfs per channel row in LDS (1024 + 128 halo pad)

// funnel16(hi, lo) = (hi:lo) >> 16  -> v_alignbit_b32
__device__ __forceinline__ uint32_t funnel16(uint32_t hi, uint32_t lo) {
  return (uint32_t)((((uint64_t)hi << 32) | (uint64_t)lo) >> 16);
}

// pack two f32 -> one dword of 2x f16 (v_cvt_pkrtz_f16_f32)
__device__ __forceinline__ uint32_t pk(float a, float b) {
  union { fp16x2 h; uint32_t u; } cv;
  cv.h = __builtin_amdgcn_cvt_pkrtz(a, b);
  return cv.u;
}

// w LDS swizzle (half-index, mult of 4): XOR chunk idx with its own bits 6-8
// breaks the c15-row -> same-bank-quad pattern of the [f][k] layout.
__device__ __forceinline__ uint32_t wswz(uint32_t e) {
  uint32_t ch = e >> 3;
  ch ^= (ch >> 6) & 7u;
  return (ch << 4) | ((e & 7u) << 1);
}

// One block = one 1024-t tile of one n:
//   stage w (16 KB f16, swizzled) + x tile (8 ch x 1152 f16) -> 1 barrier ->
//   8 waves each compute a 128-t slice (16 k-steps x 8 MFMA, sliding-window
//   fragments from one 16B-aligned LDS read pair) -> register-transpose
//   stores (alignment-exact; drain while successor blocks stage).
// Mapping (validated R1/R4): t = t0 + tlw + r + 8*c15, f = 4*g + q.
__global__ __launch_bounds__(512, 8)
void corr1d(const float* __restrict__ x, const float* __restrict__ w,
            const float* __restrict__ b, float* __restrict__ out) {
  __shared__ __align__(16) _Float16 wl[F_ * K_];   // 16 KB
  __shared__ __align__(16) _Float16 xb[C_ * XS];   // 18 KB

  const int tid  = threadIdx.x;
  const int lane = tid & 63;
  const int wv   = tid >> 6;           // 0..7
  const int c15  = lane & 15;
  const int g    = lane >> 4;

  const int n  = blockIdx.x >> 6;      // 32 n
  const int tt = blockIdx.x & 63;      // 64 tiles of 1024 t
  const int t0 = tt * TILE_T;

  const float* xn = x + (size_t)n * (C_ * W_);

  // ---- stage w: 8192 f32 -> f16 swizzled (4 f32x4 per thread) ----
  #pragma unroll
  for (int j = 0; j < 4; ++j) {
    int e = (tid + 512 * j) * 4;
    f32x4 v = *reinterpret_cast<const f32x4*>(w + e);
    u32x2 p; p[0] = pk(v[0], v[1]); p[1] = pk(v[2], v[3]);
    *reinterpret_cast<u32x2*>(reinterpret_cast<char*>(wl) + wswz((uint32_t)e)) = p;
  }

  // ---- stage x: units of f32x4; 2176 units = 8 ch x 272 ----
  #pragma unroll
  for (int j = 0; j < 4; ++j) {
    int u = tid + 512 * j;
    int ch = u / 272;
    int pos = (u - ch * 272) * 4;      // 0..1084
    int gi = t0 + pos;
    f32x4 v = (gi < W_) ? *reinterpret_cast<const f32x4*>(xn + (size_t)ch * W_ + gi)
                        : (f32x4){0.f, 0.f, 0.f, 0.f};
    u32x2 p; p[0] = pk(v[0], v[1]); p[1] = pk(v[2], v[3]);
    *reinterpret_cast<u32x2*>(reinterpret_cast<char*>(xb) + (size_t)(ch * XS + pos) * 2u) = p;
  }
  if (tid < 128) {                     // remaining 128 units
    int u = 2048 + tid;
    int ch = u / 272;
    int pos = (u - ch * 272) * 4;
    int gi = t0 + pos;
    f32x4 v = (gi < W_) ? *reinterpret_cast<const f32x4*>(xn + (size_t)ch * W_ + gi)
                        : (f32x4){0.f, 0.f, 0.f, 0.f};
    u32x2 p; p[0] = pk(v[0], v[1]); p[1] = pk(v[2], v[3]);
    *reinterpret_cast<u32x2*>(reinterpret_cast<char*>(xb) + (size_t)(ch * XS + pos) * 2u) = p;
  }

  const f32x4 bv = *reinterpret_cast<const f32x4*>(b + 4 * g);

  __syncthreads();   // the only barrier

  const int tlw = wv << 7;             // wave's 128-t slice

  f32x4 acc[8];
  #pragma unroll
  for (int r = 0; r < 8; ++r) acc[r] = (f32x4){0.f, 0.f, 0.f, 0.f};

  union Win { half8 h[2]; uint32_t d[8]; };

  // ---- K loop: 16 k-steps of 32 ----
  #pragma unroll
  for (int s = 0; s < 16; ++s) {
    const uint32_t we = (uint32_t)(c15 * K_ + 32 * s + 8 * g);
    const half8 wf = *reinterpret_cast<const half8*>(
                         reinterpret_cast<const char*>(wl) + wswz(we));
    const int c  = s >> 1;
    const int jb = (s & 1) * 32;
    const int A0 = tlw + 8 * c15 + jb + 8 * g;   // mult of 8 -> 16B aligned
    Win win;
    win.h[0] = *reinterpret_cast<const half8*>(xb + c * XS + A0);
    win.h[1] = *reinterpret_cast<const half8*>(xb + c * XS + A0 + 8);
    #pragma unroll
    for (int r = 0; r < 8; ++r) {
      union { uint32_t d[4]; half8 h; } fr;
      const int m = r >> 1;
      if ((r & 1) == 0) {
        fr.d[0] = win.d[m];     fr.d[1] = win.d[m + 1];
        fr.d[2] = win.d[m + 2]; fr.d[3] = win.d[m + 3];
      } else {
        fr.d[0] = funnel16(win.d[m + 1], win.d[m]);
        fr.d[1] = funnel16(win.d[m + 2], win.d[m + 1]);
        fr.d[2] = funnel16(win.d[m + 3], win.d[m + 2]);
        fr.d[3] = funnel16(win.d[m + 4], win.d[m + 3]);
      }
      acc[r] = __builtin_amdgcn_mfma_f32_16x16x32_f16(wf, fr.h, acc[r], 0, 0, 0);
    }
  }

  // ---- epilogue: register-transpose stores, alignment-exact per q ----
  // (row + T) mod 16 = 4*((f + T) mod 4) = 4*q  since T is a multiple of 8.
  const int T = t0 + tlw + 8 * c15;
  float* outn = out + (size_t)n * F_ * OW_;
  #pragma unroll
  for (int q = 0; q < 4; ++q) {
    const float bias = 8.0f * bv[q];   // reference adds bias C times
    float sv[8];
    #pragma unroll
    for (int j = 0; j < 8; ++j) sv[j] = acc[j][q] + bias;
    float* row = outn + (size_t)(4 * g + q) * OW_ + T;
    if (T + 8 <= OW_) {
      if (q == 0) {            // 16B aligned
        *reinterpret_cast<f32x4*>(row)     = (f32x4){sv[0], sv[1], sv[2], sv[3]};
        *reinterpret_cast<f32x4*>(row + 4) = (f32x4){sv[4], sv[5], sv[6], sv[7]};
      } else if (q == 2) {     // 8B aligned
        *reinterpret_cast<f32x2*>(row)     = (f32x2){sv[0], sv[1]};
        *reinterpret_cast<f32x2*>(row + 2) = (f32x2){sv[2], sv[3]};
        *reinterpret_cast<f32x2*>(row + 4) = (f32x2){sv[4], sv[5]};
        *reinterpret_cast<f32x2*>(row + 6) = (f32x2){sv[6], sv[7]};
      } else {                 // q odd: dword, then 8B-aligned pairs
        row[0] = sv[0];
        *reinterpret_cast<f32x2*>(row + 1) = (f32x2){sv[1], sv[2]};
        *reinterpret_cast<f32x2*>(row + 3) = (f32x2){sv[3], sv[4]};
        *reinterpret_cast<f32x2*>(row + 5) = (f32x2){sv[5], sv[6]};
        row[7] = sv[7];
      }
    } else {
      #pragma unroll
      for (int j = 0; j < 8; ++j) if (T + j < OW_) row[j] = sv[j];
    }
  }
}

extern "C" void kernel_launch(void* const* d_in, const int* in_sizes, int n_in,
                              void* d_out, int out_size, void* d_ws, size_t ws_size,
                              hipStream_t stream) {
  (void)in_sizes; (void)n_in; (void)out_size; (void)d_ws; (void)ws_size;
  const float* x = (const float*)d_in[0];
  const float* w = (const float*)d_in[1];
  const float* b = (const float*)d_in[2];
  float* out = (float*)d_out;
  corr1d<<<dim3(32 * 64), dim3(512), 0, stream>>>(x, w, b, out);
}

// Round 7
// 53.013 us; speedup vs baseline: 2.2679x; 1.1088x over previous
//
#include <hip/hip_runtime.h>
#include <stdint.h>

typedef _Float16 half8 __attribute__((ext_vector_type(8)));
typedef __fp16 fp16x2 __attribute__((ext_vector_type(2)));
typedef float f32x4 __attribute__((ext_vector_type(4)));
typedef float f32x2 __attribute__((ext_vector_type(2)));
typedef uint32_t u32x2 __attribute__((ext_vector_type(2)));

#define N_ 32
#define C_ 8
#define W_ 65536
#define F_ 16
#define OW_ 65473
#define K_ 512
#define TILE_T 1024
#define XS 1152              // halfs per channel row in LDS (1024 + 128 halo)

// funnel16(hi, lo) = (hi:lo) >> 16  -> v_alignbit_b32
__device__ __forceinline__ uint32_t funnel16(uint32_t hi, uint32_t lo) {
  return (uint32_t)((((uint64_t)hi << 32) | (uint64_t)lo) >> 16);
}

// pack two f32 -> one dword of 2x f16 (v_cvt_pkrtz_f16_f32)
__device__ __forceinline__ uint32_t pk(float a, float b) {
  union { fp16x2 h; uint32_t u; } cv;
  cv.h = __builtin_amdgcn_cvt_pkrtz(a, b);
  return cv.u;
}

// w LDS swizzle (half-index, mult of 4): XOR chunk idx with bits 6-8 (=c15&7)
__device__ __forceinline__ uint32_t wswz(uint32_t e) {
  uint32_t ch = e >> 3;
  ch ^= (ch >> 6) & 7u;
  return (ch << 4) | ((e & 7u) << 1);
}

__device__ __forceinline__ f32x4 ldx(const float* p) {
  return *reinterpret_cast<const f32x4*>(p);
}

// One block = one 1024-t tile of one n. Stage w (swizzled f16) + x tile ->
// 1 barrier -> 8 waves x 128-t slices (16 k-steps x 8 MFMA via sliding-window
// fragments) -> register-transpose stores (alignment-exact per q).
// Mapping (validated R1/R4/R5): t = t0 + tlw + r + 8*c15, f = 4*g + q.
template<bool TAIL>
__device__ __forceinline__ void block_job(const float* __restrict__ x,
                                          const float* __restrict__ w,
                                          const float* __restrict__ b,
                                          float* __restrict__ out,
                                          _Float16* wl, _Float16* xb,
                                          int n, int t0) {
  const int tid  = threadIdx.x;
  const int lane = tid & 63;
  const int wv   = tid >> 6;
  const int c15  = lane & 15;
  const int g    = lane >> 4;

  const float* xn = x + (size_t)n * (C_ * W_);

  // ---- stage w: 8192 f32 -> f16 swizzled ----
  #pragma unroll
  for (int j = 0; j < 4; ++j) {
    int e = (tid + 512 * j) * 4;
    f32x4 v = ldx(w + e);
    u32x2 p; p[0] = pk(v[0], v[1]); p[1] = pk(v[2], v[3]);
    *reinterpret_cast<u32x2*>(reinterpret_cast<char*>(wl) + wswz((uint32_t)e)) = p;
  }

  // ---- stage x: 2176 f32x4 units = 8 ch x 272 ----
  #pragma unroll
  for (int j = 0; j < 5; ++j) {
    int u = tid + 512 * j;
    if (j == 4 && u >= 2176) break;     // only 128 threads in the 5th pass
    int ch = u / 272;
    int pos = (u - ch * 272) * 4;       // 0..1084
    int gi = t0 + pos;
    f32x4 v;
    if (TAIL) v = (gi < W_) ? ldx(xn + (size_t)ch * W_ + gi) : (f32x4){0.f,0.f,0.f,0.f};
    else      v = ldx(xn + (size_t)ch * W_ + gi);
    u32x2 p; p[0] = pk(v[0], v[1]); p[1] = pk(v[2], v[3]);
    *reinterpret_cast<u32x2*>(reinterpret_cast<char*>(xb) + (size_t)(ch * XS + pos) * 2u) = p;
  }

  const f32x4 bv = *reinterpret_cast<const f32x4*>(b + 4 * g);

  __syncthreads();   // the only barrier

  const int tlw = wv << 7;

  f32x4 acc[8];
  #pragma unroll
  for (int r = 0; r < 8; ++r) acc[r] = (f32x4){0.f, 0.f, 0.f, 0.f};

  union Win { half8 h[2]; uint32_t d[8]; };

  #pragma unroll
  for (int s = 0; s < 16; ++s) {
    const uint32_t we = (uint32_t)(c15 * K_ + 32 * s + 8 * g);
    const half8 wf = *reinterpret_cast<const half8*>(
                         reinterpret_cast<const char*>(wl) + wswz(we));
    const int c  = s >> 1;
    const int jb = (s & 1) * 32;
    const int A0 = tlw + 8 * c15 + jb + 8 * g;   // mult of 8 -> 16B aligned
    Win win;
    win.h[0] = *reinterpret_cast<const half8*>(xb + c * XS + A0);
    win.h[1] = *reinterpret_cast<const half8*>(xb + c * XS + A0 + 8);
    #pragma unroll
    for (int r = 0; r < 8; ++r) {
      union { uint32_t d[4]; half8 h; } fr;
      const int m = r >> 1;
      if ((r & 1) == 0) {
        fr.d[0] = win.d[m];     fr.d[1] = win.d[m + 1];
        fr.d[2] = win.d[m + 2]; fr.d[3] = win.d[m + 3];
      } else {
        fr.d[0] = funnel16(win.d[m + 1], win.d[m]);
        fr.d[1] = funnel16(win.d[m + 2], win.d[m + 1]);
        fr.d[2] = funnel16(win.d[m + 3], win.d[m + 2]);
        fr.d[3] = funnel16(win.d[m + 4], win.d[m + 3]);
      }
      acc[r] = __builtin_amdgcn_mfma_f32_16x16x32_f16(wf, fr.h, acc[r], 0, 0, 0);
    }
  }

  // ---- epilogue: register-transpose stores, alignment-exact per q ----
  // (row + T) mod 16 = 4*((f + T) mod 4) = 4*q  since T is a multiple of 8.
  const int T = t0 + tlw + 8 * c15;
  float* outn = out + (size_t)n * F_ * OW_;
  #pragma unroll
  for (int q = 0; q < 4; ++q) {
    const float bias = 8.0f * bv[q];   // reference adds bias C times
    float sv[8];
    #pragma unroll
    for (int j = 0; j < 8; ++j) sv[j] = acc[j][q] + bias;
    float* row = outn + (size_t)(4 * g + q) * OW_ + T;
    if (!TAIL || T + 8 <= OW_) {
      if (q == 0) {            // 16B aligned
        *reinterpret_cast<f32x4*>(row)     = (f32x4){sv[0], sv[1], sv[2], sv[3]};
        *reinterpret_cast<f32x4*>(row + 4) = (f32x4){sv[4], sv[5], sv[6], sv[7]};
      } else if (q == 2) {     // 8B aligned
        *reinterpret_cast<f32x2*>(row)     = (f32x2){sv[0], sv[1]};
        *reinterpret_cast<f32x2*>(row + 2) = (f32x2){sv[2], sv[3]};
        *reinterpret_cast<f32x2*>(row + 4) = (f32x2){sv[4], sv[5]};
        *reinterpret_cast<f32x2*>(row + 6) = (f32x2){sv[6], sv[7]};
      } else {                 // q odd: dword, then 8B-aligned pairs
        row[0] = sv[0];
        *reinterpret_cast<f32x2*>(row + 1) = (f32x2){sv[1], sv[2]};
        *reinterpret_cast<f32x2*>(row + 3) = (f32x2){sv[3], sv[4]};
        *reinterpret_cast<f32x2*>(row + 5) = (f32x2){sv[5], sv[6]};
        row[7] = sv[7];
      }
    } else {
      #pragma unroll
      for (int j = 0; j < 8; ++j) if (T + j < OW_) row[j] = sv[j];
    }
  }
}

__global__ __launch_bounds__(512, 6)
void corr1d(const float* __restrict__ x, const float* __restrict__ w,
            const float* __restrict__ b, float* __restrict__ out) {
  __shared__ __align__(16) _Float16 wl[F_ * K_];   // 16 KB
  __shared__ __align__(16) _Float16 xb[C_ * XS];   // 18 KB

  const int n  = blockIdx.x >> 6;      // 32 n
  const int tt = blockIdx.x & 63;      // 64 tiles of 1024 t
  const int t0 = tt * TILE_T;

  if (tt < 63) block_job<false>(x, w, b, out, wl, xb, n, t0);
  else         block_job<true >(x, w, b, out, wl, xb, n, t0);
}

extern "C" void kernel_launch(void* const* d_in, const int* in_sizes, int n_in,
                              void* d_out, int out_size, void* d_ws, size_t ws_size,
                              hipStream_t stream) {
  (void)in_sizes; (void)n_in; (void)out_size; (void)d_ws; (void)ws_size;
  const float* x = (const float*)d_in[0];
  const float* w = (const float*)d_in[1];
  const float* b = (const float*)d_in[2];
  float* out = (float*)d_out;
  corr1d<<<dim3(32 * 64), dim3(512), 0, stream>>>(x, w, b, out);
}